// Round 6
// baseline (8395115.625 us; speedup 1.0000x reference)
//
#include <hip/hip_runtime.h>
#include <stdint.h>

typedef unsigned int u32;
typedef unsigned short u16;
typedef unsigned long long u64;
typedef _Float16 f16;
typedef _Float16 h2_t __attribute__((ext_vector_type(2)));
typedef _Float16 f16x4 __attribute__((ext_vector_type(4)));
typedef _Float16 f16x8 __attribute__((ext_vector_type(8)));
typedef float f32x4 __attribute__((ext_vector_type(4)));
typedef float f32x16 __attribute__((ext_vector_type(16)));

#define TT 512
#define NF 128
#define NTOT (256 * TT)

// ---- ws layout (bytes) ----
#define OFF_WA0   0u          // 786432 f16 = 1,572,864
#define OFF_WA1   1572864u    // 524288 f16 = 1,048,576
#define OFF_WAH   2621440u    // 131072 f16 =   262,144
#define OFF_GSUM  2883584u    // 128 f32 (+pad)
#define OFF_GSQ   2884096u    // 128 f32 (+pad)
#define OFF_XC    2884608u    // 256 u32 (XCC handshake)
#define OFF_GH1   2885632u    // 8 groups * 4096 u64 = 262,144
#define OFF_GH2   3147776u    // 262,144
#define OFF_Y     3409920u    // 131072*128 f16 = 33,554,432

__device__ __forceinline__ float sigf(float x) { return 1.0f / (1.0f + __expf(-x)); }
__device__ __forceinline__ float tanh_fast(float x) { return 1.0f - 2.0f / (__expf(2.0f * x) + 1.0f); }

// ---------------- prep: pack weights into per-wave MFMA A-fragments; zero stats/xc/exchange ----
// Fragment k-convention kappa(h,j) = 8h + j (h = lane>>5 for 32x32, lane>>4 for 16x16).
__global__ void prep_kernel(const float* __restrict__ Wih0, const float* __restrict__ Whh0,
                            const float* __restrict__ Wih1, const float* __restrict__ Whh1,
                            const float* __restrict__ W1,
                            f16* __restrict__ WA0, f16* __restrict__ WA1, f16* __restrict__ WAH,
                            float* __restrict__ gz, u32* __restrict__ xcz, u32* __restrict__ ghz) {
    int idx = blockIdx.x * 256 + threadIdx.x;
    const int n0 = 786432, n1 = 524288, n2 = 131072;
    if (idx < n0) {
        int u = idx >> 9, r9 = idx & 511;
        int lane = r9 >> 3, j = r9 & 7;
        int ks = u % 6; u /= 6;
        int kw = u & 7, w = u >> 3;
        int lr = lane & 31, h = lane >> 5;
        int r = ((lr >> 3) << 8) + 8 * w + (lr & 7);
        int c = 96 * kw + 16 * ks + 8 * h + j;
        float v = (c < 512) ? Wih0[r * 512 + c] : Whh0[r * 256 + (c - 512)];
        WA0[idx] = (f16)v;
    } else if (idx < n0 + n1) {
        int i2 = idx - n0;
        int u = i2 >> 9, r9 = i2 & 511;
        int lane = r9 >> 3, j = r9 & 7;
        int ks = u & 3; u >>= 2;
        int kw = u & 7, w = u >> 3;
        int lr = lane & 31, h = lane >> 5;
        int r = ((lr >> 3) << 8) + 8 * w + (lr & 7);
        int k = 64 * kw + 16 * ks + 8 * h + j;
        float v = (k < 256) ? Wih1[r * 256 + k] : Whh1[r * 256 + (k - 256)];
        WA1[i2] = (f16)v;
    } else if (idx < n0 + n1 + n2) {
        int i2 = idx - n0 - n1;
        int u = i2 >> 9, r9 = i2 & 511;
        int lane = r9 >> 3, j = r9 & 7;
        int ks = u & 7, w = u >> 3;
        int m = lane & 15, hh = lane >> 4;
        int k = 32 * ks + 8 * hh + j;
        float v = (m < 4) ? W1[(4 * w + m) * 256 + k] : 0.f;
        WAH[i2] = (f16)v;
    } else if (idx < n0 + n1 + n2 + 256) {
        gz[idx - n0 - n1 - n2] = 0.f;                 // gsum[128] + gsq[128]
    } else if (idx < n0 + n1 + n2 + 512) {
        xcz[idx - n0 - n1 - n2 - 256] = 0u;           // handshake slots
    } else if (idx < n0 + n1 + n2 + 512 + 131072) {
        ghz[idx - n0 - n1 - n2 - 512] = 0u;           // gh1 + gh2 (tags cleared)
    }
}

#define MFMA32(A, BP, C) (C) = __builtin_amdgcn_mfma_f32_32x32x16_f16( \
    __builtin_bit_cast(f16x8, (A)), __builtin_bit_cast(f16x8, *(const uint4*)(BP)), (C), 0, 0, 0)

#define ZZWR(KW, C) do { \
    f32x4 v0_ = {(C)[0], (C)[1], (C)[2], (C)[3]};    *(f32x4*)&zz[KW][n32][4 * h32] = v0_; \
    f32x4 v1_ = {(C)[4], (C)[5], (C)[6], (C)[7]};    *(f32x4*)&zz[KW][n32][8 + 4 * h32] = v1_; \
    f32x4 v2_ = {(C)[8], (C)[9], (C)[10], (C)[11]};  *(f32x4*)&zz[KW][n32][16 + 4 * h32] = v2_; \
    f32x4 v3_ = {(C)[12], (C)[13], (C)[14], (C)[15]}; *(f32x4*)&zz[KW][n32][24 + 4 * h32] = v3_; } while (0)

// L2-tier exchange primitives (fast path: same-XCD WGs, sc0 = L1-bypass, served by XCD L2)
#define ISSUE8(PV, P) asm volatile( \
    "global_load_dwordx2 %0, %8, off sc0\n\t" \
    "global_load_dwordx2 %1, %9, off sc0\n\t" \
    "global_load_dwordx2 %2, %10, off sc0\n\t" \
    "global_load_dwordx2 %3, %11, off sc0\n\t" \
    "global_load_dwordx2 %4, %12, off sc0\n\t" \
    "global_load_dwordx2 %5, %13, off sc0\n\t" \
    "global_load_dwordx2 %6, %14, off sc0\n\t" \
    "global_load_dwordx2 %7, %15, off sc0" \
    : "=&v"((PV)[0]), "=&v"((PV)[1]), "=&v"((PV)[2]), "=&v"((PV)[3]), \
      "=&v"((PV)[4]), "=&v"((PV)[5]), "=&v"((PV)[6]), "=&v"((PV)[7]) \
    : "v"((P)[0]), "v"((P)[1]), "v"((P)[2]), "v"((P)[3]), \
      "v"((P)[4]), "v"((P)[5]), "v"((P)[6]), "v"((P)[7]) \
    : "memory")

#define WAIT8(PV) asm volatile("s_waitcnt vmcnt(0)" \
    : "+v"((PV)[0]), "+v"((PV)[1]), "+v"((PV)[2]), "+v"((PV)[3]), \
      "+v"((PV)[4]), "+v"((PV)[5]), "+v"((PV)[6]), "+v"((PV)[7]) :: "memory")

#define PUBLISH(DST, WORD) do { if (fast) { \
    asm volatile("global_store_dwordx2 %0, %1, off sc0" :: "v"(DST), "v"(WORD) : "memory"); \
  } else { __hip_atomic_store((DST), (WORD), __ATOMIC_RELAXED, __HIP_MEMORY_SCOPE_AGENT); } } while (0)

// poll until all 8 tags == T (fast: L2 sc0 reload; rescue/slow: agent atomics)
#define RETRY8(PV, P, T) do { \
    int gu_ = 0; \
    while (true) { \
        bool st_ = false; \
        _Pragma("unroll") \
        for (int i_ = 0; i_ < 8; ++i_) st_ |= ((u32)((PV)[i_] >> 32) != (T)); \
        if (!st_) break; \
        if (fast && gu_ < 20000) { \
            ++gu_; __builtin_amdgcn_s_sleep(1); \
            ISSUE8(PV, P); WAIT8(PV); \
        } else { \
            if (++gu_ > 100000000) break; \
            __builtin_amdgcn_s_sleep(2); \
            _Pragma("unroll") \
            for (int i_ = 0; i_ < 8; ++i_) \
                if ((u32)((PV)[i_] >> 32) != (T)) \
                    (PV)[i_] = __hip_atomic_load((P)[i_], __ATOMIC_RELAXED, __HIP_MEMORY_SCOPE_AGENT); \
        } \
    } } while (0)

// ---------------- main: 8 XCD-local groups x 32 row-slice WGs; L2-tier tag-dataflow exchange ----
__global__ __launch_bounds__(512) void lstm_group_kernel(
    const float* __restrict__ audio, const float* __restrict__ s_rt,
    const uint4* __restrict__ WA0, const uint4* __restrict__ WA1, const uint4* __restrict__ WAH,
    const float* __restrict__ bih0, const float* __restrict__ bhh0,
    const float* __restrict__ bih1, const float* __restrict__ bhh1,
    const float* __restrict__ b1, u32* __restrict__ xc,
    u64* __restrict__ gh1u, u64* __restrict__ gh2u,
    f16* __restrict__ ybuf, float* __restrict__ gsum, float* __restrict__ gsq)
{
    __shared__ f16 X[32][776];         // [b][ h2/prev_out(256) | a_t(256) | h1(256) + pad ]
    __shared__ float zz[12][32][36];   // A->0..7, L1 h2-half->8..11, L1 h1-half->0..3
    __shared__ float bc0s[32], bc1s[32], b1s[4];
    __shared__ u32 xcsh[256];
    __shared__ u32 hs[4];

    const int tid = threadIdx.x;
    const int bid = blockIdx.x;
    const int wv = tid >> 6;
    const int lane = tid & 63;
    const int n32 = lane & 31;
    const int h32 = (lane >> 5) & 1;
    const int cb = tid >> 3, cj = tid & 7;   // cell-update mapping (tid<256)

    // ---- XCD handshake: measure placement, derive XCD-local (group, slice) mapping ----
    u32 xcc;
    asm volatile("s_getreg_b32 %0, hwreg(HW_REG_XCC_ID)" : "=s"(xcc));
    if (tid == 0)
        __hip_atomic_store(&xc[bid], (xcc & 7) + 1u, __ATOMIC_RELAXED, __HIP_MEMORY_SCOPE_AGENT);
    if (tid < 256) {
        u32 v = 0; int gu = 0;
        do { v = __hip_atomic_load(&xc[tid], __ATOMIC_RELAXED, __HIP_MEMORY_SCOPE_AGENT); }
        while (v == 0 && ++gu < 100000000);
        xcsh[tid] = v - 1;
    }
    __syncthreads();
    if (tid == 0) {
        int cnt[8] = {0, 0, 0, 0, 0, 0, 0, 0};
        for (int j = 0; j < 256; ++j) cnt[xcsh[j] & 7]++;
        bool ok = true;
        for (int x = 0; x < 8; ++x) ok &= (cnt[x] == 32);
        u32 g_, w_;
        if (ok) {
            g_ = xcsh[bid] & 7;
            u32 r = 0;
            for (int j = 0; j < bid; ++j) r += ((xcsh[j] & 7) == g_);
            w_ = r;
        } else { g_ = (u32)(bid & 7); w_ = (u32)(bid >> 3); }
        hs[0] = g_; hs[1] = w_; hs[2] = ok ? 1u : 0u;
    }
    __syncthreads();
    const int g = (int)hs[0];          // group == physical XCD on fast path
    const int w = (int)hs[1];          // row-slice 0..31 within group
    const bool fast = hs[2] != 0;

    u64* const src1 = gh1u + (size_t)g * 4096;
    u64* const src2 = gh2u + (size_t)g * 4096;
    u64* p1[8]; u64* p2[8];
    #pragma unroll
    for (int i = 0; i < 8; ++i) { p1[i] = src1 + tid + 512 * i; p2[i] = src2 + tid + 512 * i; }

    // ---- persistent A-fragments ----
    uint4 a0[6], a1[4], ah[8] = {};
    #pragma unroll
    for (int ks = 0; ks < 6; ++ks) a0[ks] = WA0[((w * 8 + wv) * 6 + ks) * 64 + lane];
    #pragma unroll
    for (int ks = 0; ks < 4; ++ks) a1[ks] = WA1[((w * 8 + wv) * 4 + ks) * 64 + lane];
    if (wv == 0) {
        #pragma unroll
        for (int ks = 0; ks < 8; ++ks) ah[ks] = WAH[(w * 8 + ks) * 64 + lane];
    }

    if (tid < 32) {
        int r = ((tid >> 3) << 8) + 8 * w + (tid & 7);
        bc0s[tid] = bih0[r] + bhh0[r];
        bc1s[tid] = bih1[r] + bhh1[r];
    }
    if (tid < 4) b1s[tid] = b1[4 * w + tid];

    // ---- init X: prev_out = mean(s_rt), a_0, h1 = 0 ----
    for (int it = tid; it < 32 * 256; it += 512) {
        int b = it >> 8, c = it & 255;
        const float* sp = s_rt + ((size_t)(32 * g + b) * 16) * 256 + c;
        float s = 0.f;
        #pragma unroll
        for (int l = 0; l < 16; ++l) s += sp[l * 256];
        X[b][c] = (f16)(s * 0.0625f);
        X[b][256 + c] = (f16)audio[((size_t)(32 * g + b) * 512) * 256 + c];
    }
    for (int it = tid; it < 32 * 128; it += 512) {
        int b = it >> 7, q = it & 127;
        ((u32*)&X[b][512])[q] = 0u;
    }
    float c1 = 0.f, c2 = 0.f;
    float ys0 = 0, ys1 = 0, ys2 = 0, ys3 = 0, yq0 = 0, yq1 = 0, yq2 = 0, yq3 = 0;
    __syncthreads();

    for (int t = 0; t < TT; ++t) {
        const u32 T = (u32)(t + 1);
        // prefetch audio(t+1) into registers (in flight across the step)
        float4 av0, av1, av2, av3;
        if (t + 1 < TT) {
            const float4* a4 = (const float4*)audio;
            int b0 = tid >> 6, q0 = tid & 63;
            size_t base = ((size_t)(t + 1)) * 64 + q0;
            av0 = a4[(size_t)(32 * g + b0) * 32768 + base];
            av1 = a4[(size_t)(32 * g + b0 + 8) * 32768 + base];
            av2 = a4[(size_t)(32 * g + b0 + 16) * 32768 + base];
            av3 = a4[(size_t)(32 * g + b0 + 24) * 32768 + base];
        }
        // ---- A: layer0 gates, full K=768, K-split over 8 waves -> zz[0..7] ----
        {
            f32x16 C = {};
            #pragma unroll
            for (int ks = 0; ks < 6; ++ks)
                MFMA32(a0[ks], &X[n32][96 * wv + 16 * ks + 8 * h32], C);
            ZZWR(wv, C);
        }
        __syncthreads();   // #1
        // ---- B: cell L0 + direct tagged publish ----
        if (tid < 256) {
            float z0 = bc0s[cj], z1 = bc0s[8 + cj], z2 = bc0s[16 + cj], z3 = bc0s[24 + cj];
            #pragma unroll
            for (int kw = 0; kw < 8; ++kw) {
                z0 += zz[kw][cb][cj];      z1 += zz[kw][cb][8 + cj];
                z2 += zz[kw][cb][16 + cj]; z3 += zz[kw][cb][24 + cj];
            }
            float c = sigf(z1) * c1 + sigf(z0) * tanh_fast(z2);
            c1 = c;
            f16 hf = (f16)(sigf(z3) * tanh_fast(c));
            u32 hb = (u32)__builtin_bit_cast(u16, hf);
            u32 nb = (u32)__shfl_xor((int)hb, 1, 64);
            if ((tid & 1) == 0) {
                u64 word = (u64)(hb | (nb << 16)) | ((u64)T << 32);
                u64* dst = src1 + (cb * 128 + 4 * w + (cj >> 1));
                PUBLISH(dst, word);
            }
        }
        // ---- h1 window: issue polls; overlap L1 h2-half MFMA -> zz[8..11] ----
        u64 pv[8];
        if (fast) { ISSUE8(pv, p1); }
        else {
            #pragma unroll
            for (int i = 0; i < 8; ++i)
                pv[i] = __hip_atomic_load(p1[i], __ATOMIC_RELAXED, __HIP_MEMORY_SCOPE_AGENT);
        }
        if (wv >= 4) {
            f32x16 C = {};
            if (t > 0) {
                #pragma unroll
                for (int ks = 0; ks < 4; ++ks)
                    MFMA32(a1[ks], &X[n32][64 * (wv - 4) + 16 * ks + 8 * h32], C);
            }
            ZZWR(wv + 4, C);
        }
        if (fast) { WAIT8(pv); }
        RETRY8(pv, p1, T);
        #pragma unroll
        for (int i = 0; i < 8; ++i) {
            int idx = tid + 512 * i;
            *(u32*)&X[idx >> 7][512 + 2 * (idx & 127)] = (u32)pv[i];
        }
        __syncthreads();   // #2
        // ---- D: L1 h1-half (waves 0..3) -> zz[0..3] ----
        if (wv < 4) {
            f32x16 C = {};
            #pragma unroll
            for (int ks = 0; ks < 4; ++ks)
                MFMA32(a1[ks], &X[n32][512 + 64 * wv + 16 * ks + 8 * h32], C);
            ZZWR(wv, C);
        }
        __syncthreads();   // #3
        // ---- E: cell L1 + direct tagged publish ----
        if (tid < 256) {
            float z0 = bc1s[cj], z1 = bc1s[8 + cj], z2 = bc1s[16 + cj], z3 = bc1s[24 + cj];
            #pragma unroll
            for (int kw = 0; kw < 4; ++kw) {
                z0 += zz[kw][cb][cj] + zz[8 + kw][cb][cj];
                z1 += zz[kw][cb][8 + cj] + zz[8 + kw][cb][8 + cj];
                z2 += zz[kw][cb][16 + cj] + zz[8 + kw][cb][16 + cj];
                z3 += zz[kw][cb][24 + cj] + zz[8 + kw][cb][24 + cj];
            }
            float c = sigf(z1) * c2 + sigf(z0) * tanh_fast(z2);
            c2 = c;
            f16 hf = (f16)(sigf(z3) * tanh_fast(c));
            u32 hb = (u32)__builtin_bit_cast(u16, hf);
            u32 nb = (u32)__shfl_xor((int)hb, 1, 64);
            if ((tid & 1) == 0) {
                u64 word = (u64)(hb | (nb << 16)) | ((u64)T << 32);
                u64* dst = src2 + (cb * 128 + 4 * w + (cj >> 1));
                PUBLISH(dst, word);
            }
        }
        // ---- h2 window: issue polls; overlap audio(t+1) pack -> X[256..512) ----
        if (fast) { ISSUE8(pv, p2); }
        else {
            #pragma unroll
            for (int i = 0; i < 8; ++i)
                pv[i] = __hip_atomic_load(p2[i], __ATOMIC_RELAXED, __HIP_MEMORY_SCOPE_AGENT);
        }
        if (t + 1 < TT) {
            #define AST(AV, S) do { \
                int b_ = (tid >> 6) + 8 * (S); int q_ = tid & 63; \
                h2_t p0_; p0_.x = (f16)(AV).x; p0_.y = (f16)(AV).y; \
                h2_t p1_; p1_.x = (f16)(AV).z; p1_.y = (f16)(AV).w; \
                uint2 pv_; pv_.x = __builtin_bit_cast(u32, p0_); pv_.y = __builtin_bit_cast(u32, p1_); \
                *(uint2*)&X[b_][256 + 4 * q_] = pv_; } while (0)
            AST(av0, 0); AST(av1, 1); AST(av2, 2); AST(av3, 3);
        }
        if (fast) { WAIT8(pv); }
        RETRY8(pv, p2, T);
        #pragma unroll
        for (int i = 0; i < 8; ++i) {
            int idx = tid + 512 * i;
            *(u32*)&X[idx >> 7][2 * (idx & 127)] = (u32)pv[i];
        }
        __syncthreads();   // #4
        // ---- G: head on wave 0 (16x16x32, M=4 padded); others run ahead into A(t+1) ----
        if (wv == 0) {
            #pragma unroll
            for (int nt = 0; nt < 2; ++nt) {
                f32x4 C = {};
                #pragma unroll
                for (int ks = 0; ks < 8; ++ks)
                    C = __builtin_amdgcn_mfma_f32_16x16x32_f16(
                        __builtin_bit_cast(f16x8, ah[ks]),
                        __builtin_bit_cast(f16x8,
                            *(const uint4*)&X[nt * 16 + (lane & 15)][32 * ks + 8 * ((lane >> 4) & 3)]),
                        C, 0, 0, 0);
                if (lane < 16) {
                    float y0 = C[0] + b1s[0], y1 = C[1] + b1s[1];
                    float y2 = C[2] + b1s[2], y3 = C[3] + b1s[3];
                    ys0 += y0; yq0 += y0 * y0; ys1 += y1; yq1 += y1 * y1;
                    ys2 += y2; yq2 += y2 * y2; ys3 += y3; yq3 += y3 * y3;
                    f16x4 yp; yp[0] = (f16)y0; yp[1] = (f16)y1; yp[2] = (f16)y2; yp[3] = (f16)y3;
                    int b = nt * 16 + lane;
                    ((u64*)ybuf)[((size_t)(g * 32 + b) * 512 + t) * 32 + w] = __builtin_bit_cast(u64, yp);
                }
            }
        }
    }
    // ---- BN stats reduce (wave 0, lanes 0..15) ----
    if (wv == 0 && lane < 16) {
        #pragma unroll
        for (int m = 8; m >= 1; m >>= 1) {
            ys0 += __shfl_xor(ys0, m, 64); ys1 += __shfl_xor(ys1, m, 64);
            ys2 += __shfl_xor(ys2, m, 64); ys3 += __shfl_xor(ys3, m, 64);
            yq0 += __shfl_xor(yq0, m, 64); yq1 += __shfl_xor(yq1, m, 64);
            yq2 += __shfl_xor(yq2, m, 64); yq3 += __shfl_xor(yq3, m, 64);
        }
        if (lane == 0) {
            atomicAdd(&gsum[4 * w + 0], ys0); atomicAdd(&gsum[4 * w + 1], ys1);
            atomicAdd(&gsum[4 * w + 2], ys2); atomicAdd(&gsum[4 * w + 3], ys3);
            atomicAdd(&gsq[4 * w + 0], yq0); atomicAdd(&gsq[4 * w + 1], yq1);
            atomicAdd(&gsq[4 * w + 2], yq2); atomicAdd(&gsq[4 * w + 3], yq3);
        }
    }
}

// ---------------- final head: BN(train) + ReLU + Linear(128->6) ----------------
__global__ __launch_bounds__(256) void head_kernel(
    const f16* __restrict__ ybuf, const float* __restrict__ gsum, const float* __restrict__ gsq,
    const float* __restrict__ gamma, const float* __restrict__ beta,
    const float* __restrict__ W2, const float* __restrict__ b2,
    float* __restrict__ out)
{
    __shared__ float sc[NF], sh[NF], W2s[6 * NF], b2s[6];
    const int tid = threadIdx.x;
    if (tid < NF) {
        const float invN = 1.f / (float)NTOT;
        float mu = gsum[tid] * invN;
        float var = gsq[tid] * invN - mu * mu;
        float iv = rsqrtf(var + 1e-5f);
        float s = gamma[tid] * iv;
        sc[tid] = s;
        sh[tid] = beta[tid] - mu * s;
    }
    for (int i = tid; i < 6 * NF; i += 256) W2s[i] = W2[i];
    if (tid < 6) b2s[tid] = b2[tid];
    __syncthreads();

    size_t n = (size_t)blockIdx.x * 256 + tid;
    const h2_t* yr = (const h2_t*)(ybuf + n * NF);
    float a0 = b2s[0], a1 = b2s[1], a2 = b2s[2], a3 = b2s[3], a4 = b2s[4], a5 = b2s[5];
    #pragma unroll 8
    for (int p = 0; p < 64; ++p) {
        h2_t v = yr[p];
        int f0 = 2 * p, f1 = 2 * p + 1;
        float v0 = fmaxf(fmaf((float)v.x, sc[f0], sh[f0]), 0.f);
        float v1 = fmaxf(fmaf((float)v.y, sc[f1], sh[f1]), 0.f);
        a0 = fmaf(v0, W2s[0 * NF + f0], a0); a0 = fmaf(v1, W2s[0 * NF + f1], a0);
        a1 = fmaf(v0, W2s[1 * NF + f0], a1); a1 = fmaf(v1, W2s[1 * NF + f1], a1);
        a2 = fmaf(v0, W2s[2 * NF + f0], a2); a2 = fmaf(v1, W2s[2 * NF + f1], a2);
        a3 = fmaf(v0, W2s[3 * NF + f0], a3); a3 = fmaf(v1, W2s[3 * NF + f1], a3);
        a4 = fmaf(v0, W2s[4 * NF + f0], a4); a4 = fmaf(v1, W2s[4 * NF + f1], a4);
        a5 = fmaf(v0, W2s[5 * NF + f0], a5); a5 = fmaf(v1, W2s[5 * NF + f1], a5);
    }
    float* op = out + n * 6;
    op[0] = a0; op[1] = a1; op[2] = a2; op[3] = a3; op[4] = a4; op[5] = a5;
}

extern "C" void kernel_launch(void* const* d_in, const int* in_sizes, int n_in,
                              void* d_out, int out_size, void* d_ws, size_t ws_size,
                              hipStream_t stream) {
    const float* audio = (const float*)d_in[1];
    const float* s_rt  = (const float*)d_in[2];
    const float* Wih0  = (const float*)d_in[3];
    const float* Whh0  = (const float*)d_in[4];
    const float* bih0  = (const float*)d_in[5];
    const float* bhh0  = (const float*)d_in[6];
    const float* Wih1  = (const float*)d_in[7];
    const float* Whh1  = (const float*)d_in[8];
    const float* bih1  = (const float*)d_in[9];
    const float* bhh1  = (const float*)d_in[10];
    const float* W1    = (const float*)d_in[11];
    const float* b1    = (const float*)d_in[12];
    const float* gamma = (const float*)d_in[13];
    const float* beta  = (const float*)d_in[14];
    const float* W2    = (const float*)d_in[15];
    const float* b2    = (const float*)d_in[16];

    char* ws = (char*)d_ws;
    f16* WA0    = (f16*)(ws + OFF_WA0);
    f16* WA1    = (f16*)(ws + OFF_WA1);
    f16* WAH    = (f16*)(ws + OFF_WAH);
    float* gsum = (float*)(ws + OFF_GSUM);
    float* gsq  = (float*)(ws + OFF_GSQ);
    u32* xc     = (u32*)(ws + OFF_XC);
    u64* gh1u   = (u64*)(ws + OFF_GH1);
    u64* gh2u   = (u64*)(ws + OFF_GH2);
    f16* ybuf   = (f16*)(ws + OFF_Y);
    float* out  = (float*)d_out;

    // prep: 786432 + 524288 + 131072 + 256 + 256 + 131072 = 1,573,376 = 6146 * 256
    prep_kernel<<<6146, 256, 0, stream>>>(Wih0, Whh0, Wih1, Whh1, W1,
                                          WA0, WA1, WAH, gsum, xc, (u32*)gh1u);

    lstm_group_kernel<<<256, 512, 0, stream>>>(audio, s_rt,
                                               (const uint4*)WA0, (const uint4*)WA1, (const uint4*)WAH,
                                               bih0, bhh0, bih1, bhh1, b1, xc,
                                               gh1u, gh2u, ybuf, gsum, gsq);

    head_kernel<<<NTOT / 256, 256, 0, stream>>>(ybuf, gsum, gsq, gamma, beta, W2, b2, out);
}

// Round 7
// 3690.183 us; speedup vs baseline: 2274.9861x; 2274.9861x over previous
//
#include <hip/hip_runtime.h>
#include <stdint.h>

typedef unsigned int u32;
typedef unsigned short u16;
typedef unsigned long long u64;
typedef _Float16 f16;
typedef _Float16 h2_t __attribute__((ext_vector_type(2)));
typedef _Float16 f16x4 __attribute__((ext_vector_type(4)));
typedef _Float16 f16x8 __attribute__((ext_vector_type(8)));
typedef float f32x4 __attribute__((ext_vector_type(4)));
typedef float f32x16 __attribute__((ext_vector_type(16)));

#define TT 512
#define NF 128
#define NTOT (256 * TT)

// ---- ws layout (bytes) ----
#define OFF_WA0   0u          // 786432 f16 = 1,572,864
#define OFF_WA1   1572864u    // 524288 f16 = 1,048,576
#define OFF_WAH   2621440u    // 131072 f16 =   262,144
#define OFF_GSUM  2883584u    // 128 f32 (+pad)
#define OFF_GSQ   2884096u    // 128 f32 (+pad)
#define OFF_CTR   2884608u    // 512 u32 (16 counters, 128B apart)
#define OFF_GH1   2886656u    // 8 groups * 2048 u64 = 131,072
#define OFF_GH2   3017728u    // 131,072
#define OFF_Y     3148800u    // 131072*128 f16 = 33,554,432

__device__ __forceinline__ float sigf(float x) { return 1.0f / (1.0f + __expf(-x)); }
__device__ __forceinline__ float tanh_fast(float x) { return 1.0f - 2.0f / (__expf(2.0f * x) + 1.0f); }

// ---------------- prep: pack weights into per-wave MFMA A-fragments ----------------
// Per-wave k-column ownership: wave wv owns cols [32wv,32wv+32) of each segment.
// L0 ks: 0,1 = h2/prev_out; 2,3 = audio; 4,5 = h1.   L1 ks: 0,1 = h1; 2,3 = h2.
// kappa(h,j) = 8h + j (h = lane>>5 for 32x32, lane>>4 for 16x16) — bijection, self-consistent.
__global__ void prep_kernel(const float* __restrict__ Wih0, const float* __restrict__ Whh0,
                            const float* __restrict__ Wih1, const float* __restrict__ Whh1,
                            const float* __restrict__ W1,
                            f16* __restrict__ WA0, f16* __restrict__ WA1, f16* __restrict__ WAH,
                            float* __restrict__ gz, u32* __restrict__ ctr) {
    int idx = blockIdx.x * 256 + threadIdx.x;
    const int n0 = 786432, n1 = 524288, n2 = 131072;
    if (idx < n0) {
        int u = idx >> 9, r9 = idx & 511;
        int lane = r9 >> 3, j = r9 & 7;
        int ks = u % 6; u /= 6;
        int wv = u & 7, w = u >> 3;
        int lr = lane & 31, h = lane >> 5;
        int r = ((lr >> 3) << 8) + 8 * w + (lr & 7);
        int seg = ks >> 1, sig = ks & 1;
        int c = 256 * seg + 32 * wv + 16 * sig + 8 * h + j;
        float v = (c < 512) ? Wih0[r * 512 + c] : Whh0[r * 256 + (c - 512)];
        WA0[idx] = (f16)v;
    } else if (idx < n0 + n1) {
        int i2 = idx - n0;
        int lane = (i2 >> 3) & 63, j = i2 & 7;
        int ks = (i2 >> 9) & 3, wv = (i2 >> 11) & 7, w = i2 >> 14;
        int lr = lane & 31, h = lane >> 5;
        int r = ((lr >> 3) << 8) + 8 * w + (lr & 7);
        int sig = ks & 1;
        int c = 32 * wv + 16 * sig + 8 * h + j;
        float v = (ks >> 1) ? Whh1[r * 256 + c] : Wih1[r * 256 + c];
        WA1[i2] = (f16)v;
    } else if (idx < n0 + n1 + n2) {
        int i2 = idx - n0 - n1;
        int u = i2 >> 9, r9 = i2 & 511;
        int lane = r9 >> 3, j = r9 & 7;
        int ks = u & 7, w = u >> 3;
        int m = lane & 15, hh = lane >> 4;
        int k = 32 * ks + 8 * hh + j;
        float v = (m < 4) ? W1[(4 * w + m) * 256 + k] : 0.f;
        WAH[i2] = (f16)v;
    } else if (idx < n0 + n1 + n2 + 256) {
        gz[idx - n0 - n1 - n2] = 0.f;     // gsum[128] + gsq[128]
    } else if (idx < n0 + n1 + n2 + 256 + 512) {
        ctr[idx - n0 - n1 - n2 - 256] = 0u;
    }
}

#define MFMA32L(A, BP, C) (C) = __builtin_amdgcn_mfma_f32_32x32x16_f16( \
    __builtin_bit_cast(f16x8, (A)), __builtin_bit_cast(f16x8, *(const uint4*)(BP)), (C), 0, 0, 0)
#define MFMA32R(A, B, C) (C) = __builtin_amdgcn_mfma_f32_32x32x16_f16( \
    __builtin_bit_cast(f16x8, (A)), __builtin_bit_cast(f16x8, (B)), (C), 0, 0, 0)

#define ZZWR(KW, C) do { \
    f32x4 v0_ = {(C)[0], (C)[1], (C)[2], (C)[3]};    *(f32x4*)&zz[KW][n32][4 * h32] = v0_; \
    f32x4 v1_ = {(C)[4], (C)[5], (C)[6], (C)[7]};    *(f32x4*)&zz[KW][n32][8 + 4 * h32] = v1_; \
    f32x4 v2_ = {(C)[8], (C)[9], (C)[10], (C)[11]};  *(f32x4*)&zz[KW][n32][16 + 4 * h32] = v2_; \
    f32x4 v3_ = {(C)[12], (C)[13], (C)[14], (C)[15]}; *(f32x4*)&zz[KW][n32][24 + 4 * h32] = v3_; } while (0)

// ---------------- main: 8 groups x 32 row-slice WGs; counter-signaled reg-direct exchange ----
__global__ __launch_bounds__(512) void lstm_group_kernel(
    const float* __restrict__ audio, const float* __restrict__ s_rt,
    const uint4* __restrict__ WA0, const uint4* __restrict__ WA1, const uint4* __restrict__ WAH,
    const float* __restrict__ bih0, const float* __restrict__ bhh0,
    const float* __restrict__ bih1, const float* __restrict__ bhh1,
    const float* __restrict__ b1, u32* __restrict__ ctr,
    u64* __restrict__ gh1u, u64* __restrict__ gh2u,
    f16* __restrict__ ybuf, float* __restrict__ gsum, float* __restrict__ gsq)
{
    __shared__ f16 Xa[32][264];        // audio(t) staged          16,896 B
    __shared__ f16 Xh2[32][264];       // h2(t) staged (head only) 16,896 B
    __shared__ float zz[8][32][36];    // per-wave partials        36,864 B
    __shared__ f16 hst[32][8];         //    512 B
    __shared__ float bc0s[32], bc1s[32], b1s[4];
    __shared__ float pad_[2700];       // force 1 WG/CU (total LDS > 80 KiB)

    const int tid = threadIdx.x;
    const int w = blockIdx.x >> 3;     // row-slice 0..31
    const int g = blockIdx.x & 7;      // group 0..7
    const int wv = tid >> 6;
    const int lane = tid & 63;
    const int n32 = lane & 31;
    const int h32 = (lane >> 5) & 1;
    const int ct = tid - 256;          // cell threads = waves 4..7
    const int cb = ct >> 3, cj = ct & 7;

    if (tid == 0) { volatile float* vp = pad_; vp[0] = 0.f; }

    u32* const ctr1 = ctr + (g * 2 + 0) * 32;
    u32* const ctr2 = ctr + (g * 2 + 1) * 32;
    u64* const src1 = gh1u + (size_t)g * 2048;
    u64* const src2 = gh2u + (size_t)g * 2048;
    const size_t gbase = (size_t)n32 * 64 + 8 * wv + 2 * h32;   // consumer word base

    // ---- persistent A-fragments ----
    uint4 a0[6], a1[4], ah[8] = {};
    #pragma unroll
    for (int ks = 0; ks < 6; ++ks) a0[ks] = WA0[((w * 8 + wv) * 6 + ks) * 64 + lane];
    #pragma unroll
    for (int ks = 0; ks < 4; ++ks) a1[ks] = WA1[((w * 8 + wv) * 4 + ks) * 64 + lane];
    if (wv < 2) {
        #pragma unroll
        for (int ks = 0; ks < 8; ++ks) ah[ks] = WAH[(w * 8 + ks) * 64 + lane];
    }

    if (tid < 32) {
        int r = ((tid >> 3) << 8) + 8 * w + (tid & 7);
        bc0s[tid] = bih0[r] + bhh0[r];
        bc1s[tid] = bih1[r] + bhh1[r];
    }
    if (tid < 4) b1s[tid] = b1[4 * w + tid];

    // ---- init: prev_out -> Xh2, audio(0) -> Xa ----
    for (int it = tid; it < 32 * 256; it += 512) {
        int b = it >> 8, c = it & 255;
        const float* sp = s_rt + ((size_t)(32 * g + b) * 16) * 256 + c;
        float s = 0.f;
        #pragma unroll
        for (int l = 0; l < 16; ++l) s += sp[l * 256];
        Xh2[b][c] = (f16)(s * 0.0625f);
        Xa[b][c] = (f16)audio[((size_t)(32 * g + b) * 512) * 256 + c];
    }
    __syncthreads();

    // initial fragments / accumulators
    uint4 f20 = *(const uint4*)&Xh2[n32][32 * wv + 8 * h32];          // h2/prev_out frag sig=0
    uint4 f21 = *(const uint4*)&Xh2[n32][32 * wv + 16 + 8 * h32];     // sig=1
    uint4 f10 = {0, 0, 0, 0}, f11 = {0, 0, 0, 0};                     // h1(-1) = 0
    f32x16 aAcc = {};
    MFMA32L(a0[2], &Xa[n32][32 * wv + 8 * h32], aAcc);                // audio(0) part
    MFMA32L(a0[3], &Xa[n32][32 * wv + 16 + 8 * h32], aAcc);

    float c1 = 0.f, c2 = 0.f;
    float ys0 = 0, ys1 = 0, ys2 = 0, ys3 = 0, yq0 = 0, yq1 = 0, yq2 = 0, yq3 = 0;

    for (int t = 0; t < TT; ++t) {
        const u32 T = (u32)(t + 1);
        // prefetch audio(t+1) into registers
        float4 av0, av1, av2, av3;
        if (t + 1 < TT) {
            const float4* a4 = (const float4*)audio;
            int b0 = tid >> 6, q0 = tid & 63;
            size_t base = ((size_t)(t + 1)) * 64 + q0;
            av0 = a4[(size_t)(32 * g + b0) * 32768 + base];
            av1 = a4[(size_t)(32 * g + b0 + 8) * 32768 + base];
            av2 = a4[(size_t)(32 * g + b0 + 16) * 32768 + base];
            av3 = a4[(size_t)(32 * g + b0 + 24) * 32768 + base];
        }
        // ---- A-finish: add h2(t-1)/prev_out part; aAcc carries audio(t)+h1(t-1) ----
        MFMA32R(a0[0], f20, aAcc);
        MFMA32R(a0[1], f21, aAcc);
        ZZWR(wv, aAcc);
        __syncthreads();   // #1
        // ---- B: cell L0 (waves 4..7) ----
        if (tid >= 256) {
            float z0 = bc0s[cj], z1 = bc0s[8 + cj], z2 = bc0s[16 + cj], z3 = bc0s[24 + cj];
            #pragma unroll
            for (int kw = 0; kw < 8; ++kw) {
                z0 += zz[kw][cb][cj];      z1 += zz[kw][cb][8 + cj];
                z2 += zz[kw][cb][16 + cj]; z3 += zz[kw][cb][24 + cj];
            }
            float c = sigf(z1) * c1 + sigf(z0) * tanh_fast(z2);
            c1 = c;
            hst[cb][cj] = (f16)(sigf(z3) * tanh_fast(c));
        }
        __syncthreads();   // #2
        // ---- window1: wave7 publishes h1; all waves compute L1 h2-part in regs ----
        if (wv == 7)
            __hip_atomic_store(src1 + (size_t)(lane >> 1) * 64 + 2 * w + (lane & 1),
                               ((const u64*)hst)[lane],
                               __ATOMIC_RELAXED, __HIP_MEMORY_SCOPE_AGENT);
        f32x16 Dacc = {};
        if (t > 0) {
            MFMA32R(a1[2], f20, Dacc);
            MFMA32R(a1[3], f21, Dacc);
        }
        if (wv == 7) {
            asm volatile("s_waitcnt vmcnt(0)" ::: "memory");
            if (lane == 0) {
                __hip_atomic_fetch_add(ctr1, 1u, __ATOMIC_RELAXED, __HIP_MEMORY_SCOPE_AGENT);
                u32 tgt = 32u * T; int gu = 0;
                while (__hip_atomic_load(ctr1, __ATOMIC_RELAXED, __HIP_MEMORY_SCOPE_AGENT) < tgt
                       && ++gu < 100000000) { __builtin_amdgcn_s_sleep(1); }
            }
        }
        __syncthreads();   // #3
        // ---- gather h1(t) directly into B-fragments ----
        {
            u64 q0 = __hip_atomic_load(src1 + gbase + 0, __ATOMIC_RELAXED, __HIP_MEMORY_SCOPE_AGENT);
            u64 q1 = __hip_atomic_load(src1 + gbase + 1, __ATOMIC_RELAXED, __HIP_MEMORY_SCOPE_AGENT);
            u64 q2 = __hip_atomic_load(src1 + gbase + 4, __ATOMIC_RELAXED, __HIP_MEMORY_SCOPE_AGENT);
            u64 q3 = __hip_atomic_load(src1 + gbase + 5, __ATOMIC_RELAXED, __HIP_MEMORY_SCOPE_AGENT);
            f10.x = (u32)q0; f10.y = (u32)(q0 >> 32); f10.z = (u32)q1; f10.w = (u32)(q1 >> 32);
            f11.x = (u32)q2; f11.y = (u32)(q2 >> 32); f11.z = (u32)q3; f11.w = (u32)(q3 >> 32);
        }
        // ---- D: L1 h1-part ----
        MFMA32R(a1[0], f10, Dacc);
        MFMA32R(a1[1], f11, Dacc);
        ZZWR(wv, Dacc);
        __syncthreads();   // #4
        // ---- E: cell L1 (waves 4..7) ----
        if (tid >= 256) {
            float z0 = bc1s[cj], z1 = bc1s[8 + cj], z2 = bc1s[16 + cj], z3 = bc1s[24 + cj];
            #pragma unroll
            for (int kw = 0; kw < 8; ++kw) {
                z0 += zz[kw][cb][cj];      z1 += zz[kw][cb][8 + cj];
                z2 += zz[kw][cb][16 + cj]; z3 += zz[kw][cb][24 + cj];
            }
            float c = sigf(z1) * c2 + sigf(z0) * tanh_fast(z2);
            c2 = c;
            hst[cb][cj] = (f16)(sigf(z3) * tanh_fast(c));
        }
        __syncthreads();   // #5
        // ---- window2: wave7 publishes h2; all write audio(t+1) -> Xa ----
        if (wv == 7)
            __hip_atomic_store(src2 + (size_t)(lane >> 1) * 64 + 2 * w + (lane & 1),
                               ((const u64*)hst)[lane],
                               __ATOMIC_RELAXED, __HIP_MEMORY_SCOPE_AGENT);
        if (t + 1 < TT) {
            #define AST(AV, S) do { \
                int b_ = (tid >> 6) + 8 * (S); int q_ = tid & 63; \
                h2_t p0_; p0_.x = (f16)(AV).x; p0_.y = (f16)(AV).y; \
                h2_t p1_; p1_.x = (f16)(AV).z; p1_.y = (f16)(AV).w; \
                uint2 pv_; pv_.x = __builtin_bit_cast(u32, p0_); pv_.y = __builtin_bit_cast(u32, p1_); \
                *(uint2*)&Xa[b_][4 * q_] = pv_; } while (0)
            AST(av0, 0); AST(av1, 1); AST(av2, 2); AST(av3, 3);
        }
        __syncthreads();   // #6
        // ---- A-precompute for t+1: audio + h1(t) parts; wave7 counts+polls ----
        aAcc = (f32x16){};
        if (t + 1 < TT) {
            MFMA32L(a0[2], &Xa[n32][32 * wv + 8 * h32], aAcc);
            MFMA32L(a0[3], &Xa[n32][32 * wv + 16 + 8 * h32], aAcc);
            MFMA32R(a0[4], f10, aAcc);
            MFMA32R(a0[5], f11, aAcc);
        }
        if (wv == 7) {
            asm volatile("s_waitcnt vmcnt(0)" ::: "memory");
            if (lane == 0) {
                __hip_atomic_fetch_add(ctr2, 1u, __ATOMIC_RELAXED, __HIP_MEMORY_SCOPE_AGENT);
                u32 tgt = 32u * T; int gu = 0;
                while (__hip_atomic_load(ctr2, __ATOMIC_RELAXED, __HIP_MEMORY_SCOPE_AGENT) < tgt
                       && ++gu < 100000000) { __builtin_amdgcn_s_sleep(1); }
            }
        }
        __syncthreads();   // #7
        // ---- gather h2(t) into fragments + stage to Xh2 for head ----
        {
            u64 q0 = __hip_atomic_load(src2 + gbase + 0, __ATOMIC_RELAXED, __HIP_MEMORY_SCOPE_AGENT);
            u64 q1 = __hip_atomic_load(src2 + gbase + 1, __ATOMIC_RELAXED, __HIP_MEMORY_SCOPE_AGENT);
            u64 q2 = __hip_atomic_load(src2 + gbase + 4, __ATOMIC_RELAXED, __HIP_MEMORY_SCOPE_AGENT);
            u64 q3 = __hip_atomic_load(src2 + gbase + 5, __ATOMIC_RELAXED, __HIP_MEMORY_SCOPE_AGENT);
            f20.x = (u32)q0; f20.y = (u32)(q0 >> 32); f20.z = (u32)q1; f20.w = (u32)(q1 >> 32);
            f21.x = (u32)q2; f21.y = (u32)(q2 >> 32); f21.z = (u32)q3; f21.w = (u32)(q3 >> 32);
            *(uint4*)&Xh2[n32][32 * wv + 8 * h32] = f20;
            *(uint4*)&Xh2[n32][32 * wv + 16 + 8 * h32] = f21;
        }
        __syncthreads();   // #8
        // ---- head: waves 0,1 (nt = wv); others run ahead into A-finish(t+1) ----
        if (wv < 2) {
            f32x4 C = {};
            #pragma unroll
            for (int ks = 0; ks < 8; ++ks)
                C = __builtin_amdgcn_mfma_f32_16x16x32_f16(
                    __builtin_bit_cast(f16x8, ah[ks]),
                    __builtin_bit_cast(f16x8,
                        *(const uint4*)&Xh2[wv * 16 + (lane & 15)][32 * ks + 8 * ((lane >> 4) & 3)]),
                    C, 0, 0, 0);
            if (lane < 16) {
                float y0 = C[0] + b1s[0], y1 = C[1] + b1s[1];
                float y2 = C[2] + b1s[2], y3 = C[3] + b1s[3];
                ys0 += y0; yq0 += y0 * y0; ys1 += y1; yq1 += y1 * y1;
                ys2 += y2; yq2 += y2 * y2; ys3 += y3; yq3 += y3 * y3;
                f16x4 yp; yp[0] = (f16)y0; yp[1] = (f16)y1; yp[2] = (f16)y2; yp[3] = (f16)y3;
                int b = wv * 16 + lane;
                ((u64*)ybuf)[((size_t)(g * 32 + b) * 512 + t) * 32 + w] = __builtin_bit_cast(u64, yp);
            }
        }
    }
    // ---- BN stats reduce (waves 0,1; lanes 0..15) ----
    if (wv < 2 && lane < 16) {
        #pragma unroll
        for (int m = 8; m >= 1; m >>= 1) {
            ys0 += __shfl_xor(ys0, m, 64); ys1 += __shfl_xor(ys1, m, 64);
            ys2 += __shfl_xor(ys2, m, 64); ys3 += __shfl_xor(ys3, m, 64);
            yq0 += __shfl_xor(yq0, m, 64); yq1 += __shfl_xor(yq1, m, 64);
            yq2 += __shfl_xor(yq2, m, 64); yq3 += __shfl_xor(yq3, m, 64);
        }
        if (lane == 0) {
            atomicAdd(&gsum[4 * w + 0], ys0); atomicAdd(&gsum[4 * w + 1], ys1);
            atomicAdd(&gsum[4 * w + 2], ys2); atomicAdd(&gsum[4 * w + 3], ys3);
            atomicAdd(&gsq[4 * w + 0], yq0); atomicAdd(&gsq[4 * w + 1], yq1);
            atomicAdd(&gsq[4 * w + 2], yq2); atomicAdd(&gsq[4 * w + 3], yq3);
        }
    }
}

// ---------------- final head: BN(train) + ReLU + Linear(128->6) ----------------
__global__ __launch_bounds__(256) void head_kernel(
    const f16* __restrict__ ybuf, const float* __restrict__ gsum, const float* __restrict__ gsq,
    const float* __restrict__ gamma, const float* __restrict__ beta,
    const float* __restrict__ W2, const float* __restrict__ b2,
    float* __restrict__ out)
{
    __shared__ float sc[NF], sh[NF], W2s[6 * NF], b2s[6];
    const int tid = threadIdx.x;
    if (tid < NF) {
        const float invN = 1.f / (float)NTOT;
        float mu = gsum[tid] * invN;
        float var = gsq[tid] * invN - mu * mu;
        float iv = rsqrtf(var + 1e-5f);
        float s = gamma[tid] * iv;
        sc[tid] = s;
        sh[tid] = beta[tid] - mu * s;
    }
    for (int i = tid; i < 6 * NF; i += 256) W2s[i] = W2[i];
    if (tid < 6) b2s[tid] = b2[tid];
    __syncthreads();

    size_t n = (size_t)blockIdx.x * 256 + tid;
    const h2_t* yr = (const h2_t*)(ybuf + n * NF);
    float a0 = b2s[0], a1 = b2s[1], a2 = b2s[2], a3 = b2s[3], a4 = b2s[4], a5 = b2s[5];
    #pragma unroll 8
    for (int p = 0; p < 64; ++p) {
        h2_t v = yr[p];
        int f0 = 2 * p, f1 = 2 * p + 1;
        float v0 = fmaxf(fmaf((float)v.x, sc[f0], sh[f0]), 0.f);
        float v1 = fmaxf(fmaf((float)v.y, sc[f1], sh[f1]), 0.f);
        a0 = fmaf(v0, W2s[0 * NF + f0], a0); a0 = fmaf(v1, W2s[0 * NF + f1], a0);
        a1 = fmaf(v0, W2s[1 * NF + f0], a1); a1 = fmaf(v1, W2s[1 * NF + f1], a1);
        a2 = fmaf(v0, W2s[2 * NF + f0], a2); a2 = fmaf(v1, W2s[2 * NF + f1], a2);
        a3 = fmaf(v0, W2s[3 * NF + f0], a3); a3 = fmaf(v1, W2s[3 * NF + f1], a3);
        a4 = fmaf(v0, W2s[4 * NF + f0], a4); a4 = fmaf(v1, W2s[4 * NF + f1], a4);
        a5 = fmaf(v0, W2s[5 * NF + f0], a5); a5 = fmaf(v1, W2s[5 * NF + f1], a5);
    }
    float* op = out + n * 6;
    op[0] = a0; op[1] = a1; op[2] = a2; op[3] = a3; op[4] = a4; op[5] = a5;
}

extern "C" void kernel_launch(void* const* d_in, const int* in_sizes, int n_in,
                              void* d_out, int out_size, void* d_ws, size_t ws_size,
                              hipStream_t stream) {
    const float* audio = (const float*)d_in[1];
    const float* s_rt  = (const float*)d_in[2];
    const float* Wih0  = (const float*)d_in[3];
    const float* Whh0  = (const float*)d_in[4];
    const float* bih0  = (const float*)d_in[5];
    const float* bhh0  = (const float*)d_in[6];
    const float* Wih1  = (const float*)d_in[7];
    const float* Whh1  = (const float*)d_in[8];
    const float* bih1  = (const float*)d_in[9];
    const float* bhh1  = (const float*)d_in[10];
    const float* W1    = (const float*)d_in[11];
    const float* b1    = (const float*)d_in[12];
    const float* gamma = (const float*)d_in[13];
    const float* beta  = (const float*)d_in[14];
    const float* W2    = (const float*)d_in[15];
    const float* b2    = (const float*)d_in[16];

    char* ws = (char*)d_ws;
    f16* WA0    = (f16*)(ws + OFF_WA0);
    f16* WA1    = (f16*)(ws + OFF_WA1);
    f16* WAH    = (f16*)(ws + OFF_WAH);
    float* gsum = (float*)(ws + OFF_GSUM);
    float* gsq  = (float*)(ws + OFF_GSQ);
    u32* ctrp   = (u32*)(ws + OFF_CTR);
    u64* gh1u   = (u64*)(ws + OFF_GH1);
    u64* gh2u   = (u64*)(ws + OFF_GH2);
    f16* ybuf   = (f16*)(ws + OFF_Y);
    float* out  = (float*)d_out;

    // prep: 786432 + 524288 + 131072 + 256 + 512 = 1,442,560 = 5635 * 256
    prep_kernel<<<5635, 256, 0, stream>>>(Wih0, Whh0, Wih1, Whh1, W1,
                                          WA0, WA1, WAH, gsum, ctrp);

    lstm_group_kernel<<<256, 512, 0, stream>>>(audio, s_rt,
                                               (const uint4*)WA0, (const uint4*)WA1, (const uint4*)WAH,
                                               bih0, bhh0, bih1, bhh1, b1, ctrp,
                                               gh1u, gh2u, ybuf, gsum, gsq);

    head_kernel<<<NTOT / 256, 256, 0, stream>>>(ybuf, gsum, gsq, gamma, beta, W2, b2, out);
}

// Round 8
// 3313.749 us; speedup vs baseline: 2533.4190x; 1.1136x over previous
//
#include <hip/hip_runtime.h>
#include <stdint.h>

typedef unsigned int u32;
typedef unsigned short u16;
typedef unsigned long long u64;
typedef _Float16 f16;
typedef _Float16 h2_t __attribute__((ext_vector_type(2)));
typedef _Float16 f16x4 __attribute__((ext_vector_type(4)));
typedef _Float16 f16x8 __attribute__((ext_vector_type(8)));
typedef float f32x4 __attribute__((ext_vector_type(4)));
typedef float f32x16 __attribute__((ext_vector_type(16)));
typedef u32 u32x4 __attribute__((ext_vector_type(4)));

#define TT 512
#define NF 128
#define NTOT (256 * TT)

// ---- ws layout (bytes) ----
#define OFF_WA0   0u          // 786432 f16 = 1,572,864
#define OFF_WA1   1572864u    // 524288 f16 = 1,048,576
#define OFF_WAH   2621440u    // 131072 f16 =   262,144
#define OFF_GSUM  2883584u    // 128 f32 (+pad)
#define OFF_GSQ   2884096u    // 128 f32 (+pad)
#define OFF_CTR   2884608u    // 512 u32 (16 counters, 128B apart)
#define OFF_GH1   2886656u    // 8 groups * 2048 u64 = 131,072
#define OFF_GH2   3017728u    // 131,072
#define OFF_Y     3148800u    // 131072*128 f16 = 33,554,432

__device__ __forceinline__ float sigf(float x) { return 1.0f / (1.0f + __expf(-x)); }
__device__ __forceinline__ float tanh_fast(float x) { return 1.0f - 2.0f / (__expf(2.0f * x) + 1.0f); }

// ---------------- prep: pack weights into per-wave MFMA A-fragments (same as r7) --------
__global__ void prep_kernel(const float* __restrict__ Wih0, const float* __restrict__ Whh0,
                            const float* __restrict__ Wih1, const float* __restrict__ Whh1,
                            const float* __restrict__ W1,
                            f16* __restrict__ WA0, f16* __restrict__ WA1, f16* __restrict__ WAH,
                            float* __restrict__ gz, u32* __restrict__ ctr) {
    int idx = blockIdx.x * 256 + threadIdx.x;
    const int n0 = 786432, n1 = 524288, n2 = 131072;
    if (idx < n0) {
        int u = idx >> 9, r9 = idx & 511;
        int lane = r9 >> 3, j = r9 & 7;
        int ks = u % 6; u /= 6;
        int wv = u & 7, w = u >> 3;
        int lr = lane & 31, h = lane >> 5;
        int r = ((lr >> 3) << 8) + 8 * w + (lr & 7);
        int seg = ks >> 1, sig = ks & 1;
        int c = 256 * seg + 32 * wv + 16 * sig + 8 * h + j;
        float v = (c < 512) ? Wih0[r * 512 + c] : Whh0[r * 256 + (c - 512)];
        WA0[idx] = (f16)v;
    } else if (idx < n0 + n1) {
        int i2 = idx - n0;
        int lane = (i2 >> 3) & 63, j = i2 & 7;
        int ks = (i2 >> 9) & 3, wv = (i2 >> 11) & 7, w = i2 >> 14;
        int lr = lane & 31, h = lane >> 5;
        int r = ((lr >> 3) << 8) + 8 * w + (lr & 7);
        int sig = ks & 1;
        int c = 32 * wv + 16 * sig + 8 * h + j;
        float v = (ks >> 1) ? Whh1[r * 256 + c] : Wih1[r * 256 + c];
        WA1[i2] = (f16)v;
    } else if (idx < n0 + n1 + n2) {
        int i2 = idx - n0 - n1;
        int u = i2 >> 9, r9 = i2 & 511;
        int lane = r9 >> 3, j = r9 & 7;
        int ks = u & 7, w = u >> 3;
        int m = lane & 15, hh = lane >> 4;
        int k = 32 * ks + 8 * hh + j;
        float v = (m < 4) ? W1[(4 * w + m) * 256 + k] : 0.f;
        WAH[i2] = (f16)v;
    } else if (idx < n0 + n1 + n2 + 256) {
        gz[idx - n0 - n1 - n2] = 0.f;     // gsum[128] + gsq[128]
    } else if (idx < n0 + n1 + n2 + 256 + 512) {
        ctr[idx - n0 - n1 - n2 - 256] = 0u;
    }
}

#define MFMA32L(A, BP, C) (C) = __builtin_amdgcn_mfma_f32_32x32x16_f16( \
    __builtin_bit_cast(f16x8, (A)), __builtin_bit_cast(f16x8, *(const uint4*)(BP)), (C), 0, 0, 0)
#define MFMA32R(A, B, C) (C) = __builtin_amdgcn_mfma_f32_32x32x16_f16( \
    __builtin_bit_cast(f16x8, (A)), __builtin_bit_cast(f16x8, (B)), (C), 0, 0, 0)

#define ZZWR(KW, C) do { \
    f32x4 v0_ = {(C)[0], (C)[1], (C)[2], (C)[3]};    *(f32x4*)&zz[KW][n32][4 * h32] = v0_; \
    f32x4 v1_ = {(C)[4], (C)[5], (C)[6], (C)[7]};    *(f32x4*)&zz[KW][n32][8 + 4 * h32] = v1_; \
    f32x4 v2_ = {(C)[8], (C)[9], (C)[10], (C)[11]};  *(f32x4*)&zz[KW][n32][16 + 4 * h32] = v2_; \
    f32x4 v3_ = {(C)[12], (C)[13], (C)[14], (C)[15]}; *(f32x4*)&zz[KW][n32][24 + 4 * h32] = v3_; } while (0)

// coherent (device-visible) wide exchange primitives
#define GATHER2(F0, F1, P0, P1) asm volatile( \
    "global_load_dwordx4 %0, %2, off sc0 sc1\n\t" \
    "global_load_dwordx4 %1, %3, off sc0 sc1\n\t" \
    "s_waitcnt vmcnt(0)" \
    : "=&v"(F0), "=&v"(F1) : "v"(P0), "v"(P1) : "memory")

#define PUBX4(PTR, DATA) asm volatile( \
    "global_store_dwordx4 %0, %1, off sc0 sc1" :: "v"(PTR), "v"(DATA) : "memory")

#define HEAD_BODY(TIDX) do { \
    f32x4 C_ = {}; \
    _Pragma("unroll") \
    for (int ks_ = 0; ks_ < 8; ++ks_) \
        C_ = __builtin_amdgcn_mfma_f32_16x16x32_f16( \
            __builtin_bit_cast(f16x8, ah[ks_]), \
            __builtin_bit_cast(f16x8, \
                *(const uint4*)&Xh2[wv * 16 + (lane & 15)][32 * ks_ + 8 * ((lane >> 4) & 3)]), \
            C_, 0, 0, 0); \
    if (lane < 16) { \
        float y0 = C_[0] + b1s[0], y1 = C_[1] + b1s[1]; \
        float y2 = C_[2] + b1s[2], y3 = C_[3] + b1s[3]; \
        ys0 += y0; yq0 += y0 * y0; ys1 += y1; yq1 += y1 * y1; \
        ys2 += y2; yq2 += y2 * y2; ys3 += y3; yq3 += y3 * y3; \
        f16x4 yp; yp[0] = (f16)y0; yp[1] = (f16)y1; yp[2] = (f16)y2; yp[3] = (f16)y3; \
        int b_ = wv * 16 + lane; \
        ((u64*)ybuf)[((size_t)(g * 32 + b_) * 512 + (TIDX)) * 32 + w] = __builtin_bit_cast(u64, yp); \
    } } while (0)

// ---------------- main: 8 groups x 32 row-slice WGs; counter-signaled wide exchange ----
__global__ __launch_bounds__(512) void lstm_group_kernel(
    const float* __restrict__ audio, const float* __restrict__ s_rt,
    const uint4* __restrict__ WA0, const uint4* __restrict__ WA1, const uint4* __restrict__ WAH,
    const float* __restrict__ bih0, const float* __restrict__ bhh0,
    const float* __restrict__ bih1, const float* __restrict__ bhh1,
    const float* __restrict__ b1, u32* __restrict__ ctr,
    u64* __restrict__ gh1u, u64* __restrict__ gh2u,
    f16* __restrict__ ybuf, float* __restrict__ gsum, float* __restrict__ gsq)
{
    __shared__ __align__(16) f16 Xa[32][264];   // audio(t) staged          16,896 B
    __shared__ __align__(16) f16 Xh2[32][264];  // h2(t) staged (head)      16,896 B
    __shared__ float zz[8][32][36];             // per-wave partials        36,864 B
    __shared__ __align__(16) f16 hst[32][8];    //    512 B
    __shared__ float bc0s[32], bc1s[32], b1s[4];
    __shared__ float pad_[2700];                // force 1 WG/CU

    const int tid = threadIdx.x;
    const int w = blockIdx.x >> 3;     // row-slice 0..31
    const int g = blockIdx.x & 7;      // group 0..7
    const int wv = tid >> 6;
    const int lane = tid & 63;
    const int n32 = lane & 31;
    const int h32 = (lane >> 5) & 1;
    const int ct = tid - 256;
    const int cb = ct >> 3, cj = ct & 7;

    if (tid == 0) { volatile float* vp = pad_; vp[0] = 0.f; }

    u32* const ctr1 = ctr + (g * 2 + 0) * 32;
    u32* const ctr2 = ctr + (g * 2 + 1) * 32;
    u64* const src1 = gh1u + (size_t)g * 2048;
    u64* const src2 = gh2u + (size_t)g * 2048;
    const size_t gbase = (size_t)n32 * 64 + 8 * wv + 2 * h32;

    // ---- persistent A-fragments ----
    uint4 a0[6], a1[4], ah[8] = {};
    #pragma unroll
    for (int ks = 0; ks < 6; ++ks) a0[ks] = WA0[((w * 8 + wv) * 6 + ks) * 64 + lane];
    #pragma unroll
    for (int ks = 0; ks < 4; ++ks) a1[ks] = WA1[((w * 8 + wv) * 4 + ks) * 64 + lane];
    if (wv < 2) {
        #pragma unroll
        for (int ks = 0; ks < 8; ++ks) ah[ks] = WAH[(w * 8 + ks) * 64 + lane];
    }

    if (tid < 32) {
        int r = ((tid >> 3) << 8) + 8 * w + (tid & 7);
        bc0s[tid] = bih0[r] + bhh0[r];
        bc1s[tid] = bih1[r] + bhh1[r];
    }
    if (tid < 4) b1s[tid] = b1[4 * w + tid];

    // ---- init: prev_out -> Xh2, audio(0) -> Xa ----
    for (int it = tid; it < 32 * 256; it += 512) {
        int b = it >> 8, c = it & 255;
        const float* sp = s_rt + ((size_t)(32 * g + b) * 16) * 256 + c;
        float s = 0.f;
        #pragma unroll
        for (int l = 0; l < 16; ++l) s += sp[l * 256];
        Xh2[b][c] = (f16)(s * 0.0625f);
        Xa[b][c] = (f16)audio[((size_t)(32 * g + b) * 512) * 256 + c];
    }
    __syncthreads();

    u32x4 f20 = *(const u32x4*)&Xh2[n32][32 * wv + 8 * h32];
    u32x4 f21 = *(const u32x4*)&Xh2[n32][32 * wv + 16 + 8 * h32];
    u32x4 f10 = {0, 0, 0, 0}, f11 = {0, 0, 0, 0};
    f32x16 aAcc = {};
    MFMA32L(a0[2], &Xa[n32][32 * wv + 8 * h32], aAcc);
    MFMA32L(a0[3], &Xa[n32][32 * wv + 16 + 8 * h32], aAcc);

    float c1 = 0.f, c2 = 0.f;
    float ys0 = 0, ys1 = 0, ys2 = 0, ys3 = 0, yq0 = 0, yq1 = 0, yq2 = 0, yq3 = 0;

    for (int t = 0; t < TT; ++t) {
        const u32 T = (u32)(t + 1);
        // ---- A-finish: h2(t-1)/prev_out part ----
        MFMA32R(a0[0], f20, aAcc);
        MFMA32R(a0[1], f21, aAcc);
        ZZWR(wv, aAcc);
        __syncthreads();   // #1
        // ---- B: cell L0 (waves 4..7) ----
        if (tid >= 256) {
            float z0 = bc0s[cj], z1 = bc0s[8 + cj], z2 = bc0s[16 + cj], z3 = bc0s[24 + cj];
            #pragma unroll
            for (int kw = 0; kw < 8; ++kw) {
                z0 += zz[kw][cb][cj];      z1 += zz[kw][cb][8 + cj];
                z2 += zz[kw][cb][16 + cj]; z3 += zz[kw][cb][24 + cj];
            }
            float c = sigf(z1) * c1 + sigf(z0) * tanh_fast(z2);
            c1 = c;
            hst[cb][cj] = (f16)(sigf(z3) * tanh_fast(c));
        }
        __syncthreads();   // #2
        // ---- window1: publish h1 (wave7, x4); Dacc h2-part; head(t-1) on waves 0,1 ----
        if (wv == 7 && lane < 32) {
            u32x4 hv = *((const u32x4*)hst + lane);
            PUBX4((void*)(src1 + (size_t)lane * 64 + 2 * w), hv);
        }
        f32x16 Dacc = {};
        if (t > 0) {
            MFMA32R(a1[2], f20, Dacc);
            MFMA32R(a1[3], f21, Dacc);
        }
        if (wv < 2 && t > 0) HEAD_BODY(t - 1);
        if (wv == 7) {
            asm volatile("s_waitcnt vmcnt(0)" ::: "memory");
            if (lane == 0) {
                __hip_atomic_fetch_add(ctr1, 1u, __ATOMIC_RELAXED, __HIP_MEMORY_SCOPE_AGENT);
                u32 tgt = 32u * T; int gu = 0;
                while (__hip_atomic_load(ctr1, __ATOMIC_RELAXED, __HIP_MEMORY_SCOPE_AGENT) < tgt
                       && ++gu < 100000000) { }
            }
        }
        __syncthreads();   // #3
        // ---- gather h1(t) -> fragments (2 x dwordx4, single wait) ----
        GATHER2(f10, f11, (const void*)(src1 + gbase), (const void*)(src1 + gbase + 4));
        // audio(t+1) prefetch (issued AFTER gather so gather's vmcnt(0) is clean)
        float4 av0, av1, av2, av3;
        if (t + 1 < TT) {
            const float4* a4 = (const float4*)audio;
            int b0 = tid >> 6, q0 = tid & 63;
            size_t base = ((size_t)(t + 1)) * 64 + q0;
            av0 = a4[(size_t)(32 * g + b0) * 32768 + base];
            av1 = a4[(size_t)(32 * g + b0 + 8) * 32768 + base];
            av2 = a4[(size_t)(32 * g + b0 + 16) * 32768 + base];
            av3 = a4[(size_t)(32 * g + b0 + 24) * 32768 + base];
        }
        // ---- D: L1 h1-part ----
        MFMA32R(a1[0], f10, Dacc);
        MFMA32R(a1[1], f11, Dacc);
        ZZWR(wv, Dacc);
        __syncthreads();   // #4
        // ---- E: cell L1 (waves 4..7) ----
        if (tid >= 256) {
            float z0 = bc1s[cj], z1 = bc1s[8 + cj], z2 = bc1s[16 + cj], z3 = bc1s[24 + cj];
            #pragma unroll
            for (int kw = 0; kw < 8; ++kw) {
                z0 += zz[kw][cb][cj];      z1 += zz[kw][cb][8 + cj];
                z2 += zz[kw][cb][16 + cj]; z3 += zz[kw][cb][24 + cj];
            }
            float c = sigf(z1) * c2 + sigf(z0) * tanh_fast(z2);
            c2 = c;
            hst[cb][cj] = (f16)(sigf(z3) * tanh_fast(c));
        }
        __syncthreads();   // #5
        // ---- window2: publish h2 (wave7, x4); audio(t+1) -> Xa ----
        if (wv == 7 && lane < 32) {
            u32x4 hv = *((const u32x4*)hst + lane);
            PUBX4((void*)(src2 + (size_t)lane * 64 + 2 * w), hv);
        }
        if (t + 1 < TT) {
            #define AST(AV, S) do { \
                int b_ = (tid >> 6) + 8 * (S); int q_ = tid & 63; \
                h2_t p0_; p0_.x = (f16)(AV).x; p0_.y = (f16)(AV).y; \
                h2_t p1_; p1_.x = (f16)(AV).z; p1_.y = (f16)(AV).w; \
                uint2 pv_; pv_.x = __builtin_bit_cast(u32, p0_); pv_.y = __builtin_bit_cast(u32, p1_); \
                *(uint2*)&Xa[b_][4 * q_] = pv_; } while (0)
            AST(av0, 0); AST(av1, 1); AST(av2, 2); AST(av3, 3);
        }
        __syncthreads();   // #6
        // ---- A-precompute for t+1: audio + h1(t) parts; wave7 counts+polls ----
        aAcc = (f32x16){};
        if (t + 1 < TT) {
            MFMA32L(a0[2], &Xa[n32][32 * wv + 8 * h32], aAcc);
            MFMA32L(a0[3], &Xa[n32][32 * wv + 16 + 8 * h32], aAcc);
            MFMA32R(a0[4], f10, aAcc);
            MFMA32R(a0[5], f11, aAcc);
        }
        if (wv == 7) {
            asm volatile("s_waitcnt vmcnt(0)" ::: "memory");
            if (lane == 0) {
                __hip_atomic_fetch_add(ctr2, 1u, __ATOMIC_RELAXED, __HIP_MEMORY_SCOPE_AGENT);
                u32 tgt = 32u * T; int gu = 0;
                while (__hip_atomic_load(ctr2, __ATOMIC_RELAXED, __HIP_MEMORY_SCOPE_AGENT) < tgt
                       && ++gu < 100000000) { }
            }
        }
        __syncthreads();   // #7
        // ---- gather h2(t) -> fragments + stage Xh2 (head reads it next step) ----
        GATHER2(f20, f21, (const void*)(src2 + gbase), (const void*)(src2 + gbase + 4));
        *(u32x4*)&Xh2[n32][32 * wv + 8 * h32] = f20;
        *(u32x4*)&Xh2[n32][32 * wv + 16 + 8 * h32] = f21;
        // no barrier here: Xh2 readers (head) are separated by syncs #1,#2 of t+1
    }
    // ---- epilogue: head for t = TT-1 ----
    __syncthreads();
    if (wv < 2) HEAD_BODY(TT - 1);
    // ---- BN stats reduce (waves 0,1; lanes 0..15) ----
    if (wv < 2 && lane < 16) {
        #pragma unroll
        for (int m = 8; m >= 1; m >>= 1) {
            ys0 += __shfl_xor(ys0, m, 64); ys1 += __shfl_xor(ys1, m, 64);
            ys2 += __shfl_xor(ys2, m, 64); ys3 += __shfl_xor(ys3, m, 64);
            yq0 += __shfl_xor(yq0, m, 64); yq1 += __shfl_xor(yq1, m, 64);
            yq2 += __shfl_xor(yq2, m, 64); yq3 += __shfl_xor(yq3, m, 64);
        }
        if (lane == 0) {
            atomicAdd(&gsum[4 * w + 0], ys0); atomicAdd(&gsum[4 * w + 1], ys1);
            atomicAdd(&gsum[4 * w + 2], ys2); atomicAdd(&gsum[4 * w + 3], ys3);
            atomicAdd(&gsq[4 * w + 0], yq0); atomicAdd(&gsq[4 * w + 1], yq1);
            atomicAdd(&gsq[4 * w + 2], yq2); atomicAdd(&gsq[4 * w + 3], yq3);
        }
    }
}

// ---------------- final head: BN(train) + ReLU + Linear(128->6) ----------------
__global__ __launch_bounds__(256) void head_kernel(
    const f16* __restrict__ ybuf, const float* __restrict__ gsum, const float* __restrict__ gsq,
    const float* __restrict__ gamma, const float* __restrict__ beta,
    const float* __restrict__ W2, const float* __restrict__ b2,
    float* __restrict__ out)
{
    __shared__ float sc[NF], sh[NF], W2s[6 * NF], b2s[6];
    const int tid = threadIdx.x;
    if (tid < NF) {
        const float invN = 1.f / (float)NTOT;
        float mu = gsum[tid] * invN;
        float var = gsq[tid] * invN - mu * mu;
        float iv = rsqrtf(var + 1e-5f);
        float s = gamma[tid] * iv;
        sc[tid] = s;
        sh[tid] = beta[tid] - mu * s;
    }
    for (int i = tid; i < 6 * NF; i += 256) W2s[i] = W2[i];
    if (tid < 6) b2s[tid] = b2[tid];
    __syncthreads();

    size_t n = (size_t)blockIdx.x * 256 + tid;
    const h2_t* yr = (const h2_t*)(ybuf + n * NF);
    float a0 = b2s[0], a1 = b2s[1], a2 = b2s[2], a3 = b2s[3], a4 = b2s[4], a5 = b2s[5];
    #pragma unroll 8
    for (int p = 0; p < 64; ++p) {
        h2_t v = yr[p];
        int f0 = 2 * p, f1 = 2 * p + 1;
        float v0 = fmaxf(fmaf((float)v.x, sc[f0], sh[f0]), 0.f);
        float v1 = fmaxf(fmaf((float)v.y, sc[f1], sh[f1]), 0.f);
        a0 = fmaf(v0, W2s[0 * NF + f0], a0); a0 = fmaf(v1, W2s[0 * NF + f1], a0);
        a1 = fmaf(v0, W2s[1 * NF + f0], a1); a1 = fmaf(v1, W2s[1 * NF + f1], a1);
        a2 = fmaf(v0, W2s[2 * NF + f0], a2); a2 = fmaf(v1, W2s[2 * NF + f1], a2);
        a3 = fmaf(v0, W2s[3 * NF + f0], a3); a3 = fmaf(v1, W2s[3 * NF + f1], a3);
        a4 = fmaf(v0, W2s[4 * NF + f0], a4); a4 = fmaf(v1, W2s[4 * NF + f1], a4);
        a5 = fmaf(v0, W2s[5 * NF + f0], a5); a5 = fmaf(v1, W2s[5 * NF + f1], a5);
    }
    float* op = out + n * 6;
    op[0] = a0; op[1] = a1; op[2] = a2; op[3] = a3; op[4] = a4; op[5] = a5;
}

extern "C" void kernel_launch(void* const* d_in, const int* in_sizes, int n_in,
                              void* d_out, int out_size, void* d_ws, size_t ws_size,
                              hipStream_t stream) {
    const float* audio = (const float*)d_in[1];
    const float* s_rt  = (const float*)d_in[2];
    const float* Wih0  = (const float*)d_in[3];
    const float* Whh0  = (const float*)d_in[4];
    const float* bih0  = (const float*)d_in[5];
    const float* bhh0  = (const float*)d_in[6];
    const float* Wih1  = (const float*)d_in[7];
    const float* Whh1  = (const float*)d_in[8];
    const float* bih1  = (const float*)d_in[9];
    const float* bhh1  = (const float*)d_in[10];
    const float* W1    = (const float*)d_in[11];
    const float* b1    = (const float*)d_in[12];
    const float* gamma = (const float*)d_in[13];
    const float* beta  = (const float*)d_in[14];
    const float* W2    = (const float*)d_in[15];
    const float* b2    = (const float*)d_in[16];

    char* ws = (char*)d_ws;
    f16* WA0    = (f16*)(ws + OFF_WA0);
    f16* WA1    = (f16*)(ws + OFF_WA1);
    f16* WAH    = (f16*)(ws + OFF_WAH);
    float* gsum = (float*)(ws + OFF_GSUM);
    float* gsq  = (float*)(ws + OFF_GSQ);
    u32* ctrp   = (u32*)(ws + OFF_CTR);
    u64* gh1u   = (u64*)(ws + OFF_GH1);
    u64* gh2u   = (u64*)(ws + OFF_GH2);
    f16* ybuf   = (f16*)(ws + OFF_Y);
    float* out  = (float*)d_out;

    // prep: 786432 + 524288 + 131072 + 256 + 512 = 1,442,560 = 5635 * 256
    prep_kernel<<<5635, 256, 0, stream>>>(Wih0, Whh0, Wih1, Whh1, W1,
                                          WA0, WA1, WAH, gsum, ctrp);

    lstm_group_kernel<<<256, 512, 0, stream>>>(audio, s_rt,
                                               (const uint4*)WA0, (const uint4*)WA1, (const uint4*)WAH,
                                               bih0, bhh0, bih1, bhh1, b1, ctrp,
                                               gh1u, gh2u, ybuf, gsum, gsq);

    head_kernel<<<NTOT / 256, 256, 0, stream>>>(ybuf, gsum, gsq, gamma, beta, W2, b2, out);
}